// Round 2
// baseline (2447.495 us; speedup 1.0000x reference)
//
#include <hip/hip_runtime.h>
#include <cmath>

#define HEADS 4
#define DM 128
#define EDIM 64

__device__ __forceinline__ float wred_max(float v) {
    #pragma unroll
    for (int off = 32; off; off >>= 1) v = fmaxf(v, __shfl_xor(v, off, 64));
    return v;
}
__device__ __forceinline__ float wred_sum(float v) {
    #pragma unroll
    for (int off = 32; off; off >>= 1) v += __shfl_xor(v, off, 64);
    return v;
}

// ---- degree count over dst ----
__global__ void k_deg(const int* __restrict__ dst, int* __restrict__ deg, int E) {
    int e = blockIdx.x * blockDim.x + threadIdx.x;
    if (e < E) atomicAdd(&deg[dst[e]], 1);
}

// ---- accumulate edge_attr into loop_attr[dst] (wave per edge, lane per feature) ----
__global__ void k_loop_accum(const int* __restrict__ dst, const float* __restrict__ ea,
                             float* __restrict__ loop_attr, int E) {
    int t = blockIdx.x * blockDim.x + threadIdx.x;
    int e = t >> 6, lane = t & 63;
    if (e < E) atomicAdd(&loop_attr[(size_t)dst[e] * EDIM + lane], ea[(size_t)e * EDIM + lane]);
}

__global__ void k_loop_div(const int* __restrict__ deg, float* __restrict__ loop_attr, int N) {
    int i = blockIdx.x * blockDim.x + threadIdx.x;
    if (i < N * EDIM) {
        int n = i >> 6;
        float d = fmaxf((float)deg[n], 1.0f);
        loop_attr[i] /= d;
    }
}

// ---- scan (row_ptr over deg+1) ----
__global__ void k_scan1(const int* __restrict__ deg, int* __restrict__ partial,
                        int* __restrict__ bsums, int N) {
    __shared__ int s[256];
    int n = blockIdx.x * 256 + threadIdx.x;
    int v = (n < N) ? (deg[n] + 1) : 0;  // +1 for self-loop
    s[threadIdx.x] = v;
    __syncthreads();
    for (int off = 1; off < 256; off <<= 1) {
        int t = (threadIdx.x >= off) ? s[threadIdx.x - off] : 0;
        __syncthreads();
        s[threadIdx.x] += t;
        __syncthreads();
    }
    if (n < N) partial[n] = s[threadIdx.x];
    if (threadIdx.x == 255) bsums[blockIdx.x] = s[255];
}
__global__ void k_scan2(int* __restrict__ bsums, int nb) {
    __shared__ int s[256];
    int v = (threadIdx.x < nb) ? bsums[threadIdx.x] : 0;
    s[threadIdx.x] = v;
    __syncthreads();
    for (int off = 1; off < 256; off <<= 1) {
        int t = (threadIdx.x >= off) ? s[threadIdx.x - off] : 0;
        __syncthreads();
        s[threadIdx.x] += t;
        __syncthreads();
    }
    bsums[threadIdx.x] = s[threadIdx.x];
}
__global__ void k_scan3(const int* __restrict__ partial, const int* __restrict__ bsums,
                        int* __restrict__ row_ptr, int N) {
    int n = blockIdx.x * 256 + threadIdx.x;
    if (n >= N) return;
    int add = (blockIdx.x > 0) ? bsums[blockIdx.x - 1] : 0;
    row_ptr[n + 1] = partial[n] + add;
    if (n == 0) row_ptr[0] = 0;
}

// ---- CSR fill (+ src_sl array) ----
__global__ void k_csr_fill(const int* __restrict__ ei, int* __restrict__ cursor,
                           int* __restrict__ eid, int* __restrict__ src_sl,
                           int E, int Etot) {
    int e = blockIdx.x * blockDim.x + threadIdx.x;
    if (e >= Etot) return;
    int s, d;
    if (e < E) { s = ei[e]; d = ei[E + e]; }
    else { s = e - E; d = e - E; }
    src_sl[e] = s;
    int pos = atomicAdd(&cursor[d], 1);
    eid[pos] = e;
}

// ---- small v precompute: v[k*12 + l*4 + h] = sum_c We_l[k,h*32+c]*ae_l[h,c] ----
__global__ void k_prep_v(const float* __restrict__ We1, const float* __restrict__ ae1,
                         const float* __restrict__ We2, const float* __restrict__ ae2,
                         const float* __restrict__ We3, const float* __restrict__ ae3,
                         float* __restrict__ vg) {
    int j = threadIdx.x;  // 768 entries, 256 threads, 3 each
    const float* Wes[3] = {We1, We2, We3};
    const float* aes[3] = {ae1, ae2, ae3};
    for (; j < EDIM * 12; j += 256) {
        int k = j / 12, m = j % 12;
        int l = m >> 2, h = m & 3;
        const float* We = Wes[l];
        const float* ae = aes[l];
        float acc = 0.f;
        #pragma unroll
        for (int c = 0; c < 32; ++c) acc += We[k * DM + h * 32 + c] * ae[h * 32 + c];
        vg[j] = acc;
    }
}

// ---- alpha_e for all 3 layers: wave per edge ----
__global__ void k_alpha_e(const float* __restrict__ ea, const float* __restrict__ loop_attr,
                          const float* __restrict__ vg, float* __restrict__ alpha_e,
                          int E, int Etot) {
    __shared__ float v[EDIM * 12];
    for (int j = threadIdx.x; j < EDIM * 12; j += 256) v[j] = vg[j];
    __syncthreads();
    int e = blockIdx.x * 4 + (threadIdx.x >> 6);
    int lane = threadIdx.x & 63;
    if (e >= Etot) return;
    float ev = (e < E) ? ea[(size_t)e * EDIM + lane] : loop_attr[(size_t)(e - E) * EDIM + lane];
    float red[12];
    #pragma unroll
    for (int m = 0; m < 12; ++m) {
        float r = ev * v[lane * 12 + m];
        #pragma unroll
        for (int off = 32; off; off >>= 1) r += __shfl_xor(r, off, 64);
        red[m] = r;
    }
    if (lane == 0) {
        #pragma unroll
        for (int m = 0; m < 12; ++m) {
            int l = m >> 2, h = m & 3;
            alpha_e[(size_t)l * Etot * HEADS + (size_t)e * HEADS + h] = red[m];
        }
    }
}

// ---- GEMM: out[M,128] = A[M,128] @ W[128,128] (+bias) ----
__global__ __launch_bounds__(256) void k_gemm128(const float* __restrict__ A,
                                                 const float* __restrict__ W,
                                                 const float* __restrict__ bias,
                                                 float* __restrict__ out, int M) {
    __shared__ float Wl[DM * DM];  // 64 KB
    int t = threadIdx.x;
    for (int i = t; i < DM * DM; i += 256) Wl[i] = W[i];
    __syncthreads();
    int col = t & 127;
    int half = t >> 7;
    int row0 = blockIdx.x * 16;
    float bv = bias ? bias[col] : 0.0f;
    for (int rl = half; rl < 16; rl += 2) {
        int row = row0 + rl;
        if (row >= M) break;
        const float* a = A + (size_t)row * DM;
        float acc = 0.f;
        #pragma unroll 8
        for (int k = 0; k < DM; ++k) acc = fmaf(a[k], Wl[k * DM + col], acc);
        out[(size_t)row * DM + col] = acc + bv;
    }
}

// ---- per-node attention coefficients ----
__global__ void k_attn_coeff(const float* __restrict__ xh, const float* __restrict__ a_s,
                             const float* __restrict__ a_d, float* __restrict__ as_n,
                             float* __restrict__ ad_n, int N) {
    int i = blockIdx.x * blockDim.x + threadIdx.x;
    if (i >= N * HEADS) return;
    int n = i >> 2, h = i & 3;
    const float* v = xh + (size_t)n * DM + h * 32;
    float s1 = 0.f, s2 = 0.f;
    #pragma unroll
    for (int c = 0; c < 32; ++c) {
        float xv = v[c];
        s1 += xv * a_s[h * 32 + c];
        s2 += xv * a_d[h * 32 + c];
    }
    as_n[i] = s1;
    ad_n[i] = s2;
}

// ---- logits + leaky_relu ----
__global__ void k_logits(const int* __restrict__ ei, const float* __restrict__ as_n,
                         const float* __restrict__ ad_n, const float* __restrict__ alpha_e_l,
                         float* __restrict__ att, int E, int Etot) {
    int e = blockIdx.x * blockDim.x + threadIdx.x;
    if (e >= Etot) return;
    int s, d;
    if (e < E) { s = ei[e]; d = ei[E + e]; }
    else { s = e - E; d = e - E; }
    #pragma unroll
    for (int h = 0; h < HEADS; ++h) {
        float l = as_n[s * HEADS + h] + ad_n[d * HEADS + h] + alpha_e_l[(size_t)e * HEADS + h];
        att[(size_t)e * HEADS + h] = (l >= 0.f) ? l : 0.2f * l;
    }
}

// ---- segment softmax over CSR (wave per node) ----
__global__ void k_softmax(const int* __restrict__ row_ptr, const int* __restrict__ eid,
                          float* __restrict__ att, int N) {
    int w = blockIdx.x * 4 + (threadIdx.x >> 6);
    int lane = threadIdx.x & 63;
    if (w >= N) return;
    int beg = row_ptr[w], end = row_ptr[w + 1];
    float m[HEADS] = {-INFINITY, -INFINITY, -INFINITY, -INFINITY};
    for (int i = beg + lane; i < end; i += 64) {
        int e = eid[i];
        #pragma unroll
        for (int h = 0; h < HEADS; ++h) m[h] = fmaxf(m[h], att[(size_t)e * HEADS + h]);
    }
    #pragma unroll
    for (int h = 0; h < HEADS; ++h) m[h] = wred_max(m[h]);
    float s[HEADS] = {0.f, 0.f, 0.f, 0.f};
    for (int i = beg + lane; i < end; i += 64) {
        int e = eid[i];
        #pragma unroll
        for (int h = 0; h < HEADS; ++h) s[h] += __expf(att[(size_t)e * HEADS + h] - m[h]);
    }
    #pragma unroll
    for (int h = 0; h < HEADS; ++h) s[h] = wred_sum(s[h]);
    for (int i = beg + lane; i < end; i += 64) {
        int e = eid[i];
        #pragma unroll
        for (int h = 0; h < HEADS; ++h)
            att[(size_t)e * HEADS + h] = __expf(att[(size_t)e * HEADS + h] - m[h]) / s[h];
    }
}

// ---- aggregation + mean + bias + residual + relu (wave per node) ----
__global__ void k_aggregate(const int* __restrict__ row_ptr, const int* __restrict__ eid,
                            const int* __restrict__ src_sl, const float* __restrict__ att,
                            const float* __restrict__ xh, const float* __restrict__ hin,
                            const float* __restrict__ bias, float* __restrict__ hout, int N) {
    int w = blockIdx.x * 4 + (threadIdx.x >> 6);
    int lane = threadIdx.x & 63;
    if (w >= N) return;
    int beg = row_ptr[w], end = row_ptr[w + 1];
    int f0 = lane, f1 = lane + 64;
    int h0 = lane >> 5;        // heads 0/1
    int h1 = 2 + (lane >> 5);  // heads 2/3
    float acc0 = 0.f, acc1 = 0.f;
    for (int i = beg; i < end; ++i) {
        int e = eid[i];
        int s = src_sl[e];
        float a0 = att[(size_t)e * HEADS + h0];
        float a1 = att[(size_t)e * HEADS + h1];
        acc0 += a0 * xh[(size_t)s * DM + f0];
        acc1 += a1 * xh[(size_t)s * DM + f1];
    }
    float cnt = (float)(end - beg);
    float o0 = acc0 / cnt + bias[f0] + hin[(size_t)w * DM + f0];
    float o1 = acc1 / cnt + bias[f1] + hin[(size_t)w * DM + f1];
    hout[(size_t)w * DM + f0] = fmaxf(o0, 0.f);
    hout[(size_t)w * DM + f1] = fmaxf(o1, 0.f);
}

extern "C" void kernel_launch(void* const* d_in, const int* in_sizes, int n_in,
                              void* d_out, int out_size, void* d_ws, size_t ws_size,
                              hipStream_t stream) {
    const float* x = (const float*)d_in[0];
    const int* ei = (const int*)d_in[1];
    const float* edge_attr = (const float*)d_in[2];
    const float* lp_W = (const float*)d_in[3];
    const float* lp_b = (const float*)d_in[4];
    int N = in_sizes[0] / DM;
    int E = in_sizes[1] / 2;
    int Etot = E + N;
    float* out = (float*)d_out;

    char* p = (char*)d_ws;
    auto alloc = [&](size_t bytes) {
        char* r = p;
        p += (bytes + 255) & ~(size_t)255;
        return r;
    };
    float* h = (float*)alloc((size_t)N * DM * 4);
    float* xh = (float*)alloc((size_t)N * DM * 4);
    float* loop_attr = (float*)alloc((size_t)N * EDIM * 4);
    float* alpha_e = (float*)alloc((size_t)3 * Etot * HEADS * 4);
    float* att = (float*)alloc((size_t)Etot * HEADS * 4);
    float* as_n = (float*)alloc((size_t)N * HEADS * 4);
    float* ad_n = (float*)alloc((size_t)N * HEADS * 4);
    float* vg = (float*)alloc(EDIM * 12 * 4);
    int* deg = (int*)alloc((size_t)N * 4);
    int* row_ptr = (int*)alloc((size_t)(N + 1) * 4);
    int* cursor = (int*)alloc((size_t)N * 4);
    int* eid = (int*)alloc((size_t)Etot * 4);
    int* src_sl = (int*)alloc((size_t)Etot * 4);
    int* partial = (int*)alloc((size_t)N * 4);
    int* bsums = (int*)alloc(256 * 4);

    hipMemsetAsync(deg, 0, (size_t)N * 4, stream);
    hipMemsetAsync(loop_attr, 0, (size_t)N * EDIM * 4, stream);

    k_deg<<<(E + 255) / 256, 256, 0, stream>>>(ei + E, deg, E);
    k_loop_accum<<<((size_t)E * 64 + 255) / 256, 256, 0, stream>>>(ei + E, edge_attr, loop_attr, E);
    k_loop_div<<<(N * EDIM + 255) / 256, 256, 0, stream>>>(deg, loop_attr, N);

    int nb = (N + 255) / 256;
    k_scan1<<<nb, 256, 0, stream>>>(deg, partial, bsums, N);
    k_scan2<<<1, 256, 0, stream>>>(bsums, nb);
    k_scan3<<<nb, 256, 0, stream>>>(partial, bsums, row_ptr, N);
    hipMemcpyAsync(cursor, row_ptr, (size_t)N * 4, hipMemcpyDeviceToDevice, stream);
    k_csr_fill<<<(Etot + 255) / 256, 256, 0, stream>>>(ei, cursor, eid, src_sl, E, Etot);

    k_prep_v<<<1, 256, 0, stream>>>((const float*)d_in[8], (const float*)d_in[9],
                                    (const float*)d_in[14], (const float*)d_in[15],
                                    (const float*)d_in[20], (const float*)d_in[21], vg);
    k_alpha_e<<<(Etot + 3) / 4, 256, 0, stream>>>(edge_attr, loop_attr, vg, alpha_e, E, Etot);

    k_gemm128<<<(N + 15) / 16, 256, 0, stream>>>(x, lp_W, lp_b, h, N);

    for (int l = 0; l < 3; ++l) {
        const float* W = (const float*)d_in[5 + 6 * l];
        const float* a_s = (const float*)d_in[6 + 6 * l];
        const float* a_d = (const float*)d_in[7 + 6 * l];
        const float* b = (const float*)d_in[10 + 6 * l];
        k_gemm128<<<(N + 15) / 16, 256, 0, stream>>>(h, W, nullptr, xh, N);
        k_attn_coeff<<<(N * HEADS + 255) / 256, 256, 0, stream>>>(xh, a_s, a_d, as_n, ad_n, N);
        k_logits<<<(Etot + 255) / 256, 256, 0, stream>>>(ei, as_n, ad_n,
                                                         alpha_e + (size_t)l * Etot * HEADS, att, E, Etot);
        k_softmax<<<(N + 3) / 4, 256, 0, stream>>>(row_ptr, eid, att, N);
        float* hout = (l == 2) ? out : h;
        k_aggregate<<<(N + 3) / 4, 256, 0, stream>>>(row_ptr, eid, src_sl, att, xh, h, b, hout, N);
    }
}

// Round 4
// 1285.239 us; speedup vs baseline: 1.9043x; 1.9043x over previous
//
#include <hip/hip_runtime.h>
#include <cmath>

#define HEADS 4
#define DM 128
#define EDIM 64

__device__ __forceinline__ float wred_max(float v) {
    #pragma unroll
    for (int off = 32; off; off >>= 1) v = fmaxf(v, __shfl_xor(v, off, 64));
    return v;
}
__device__ __forceinline__ float wred_sum(float v) {
    #pragma unroll
    for (int off = 32; off; off >>= 1) v += __shfl_xor(v, off, 64);
    return v;
}

// ---- degree count over dst ----
__global__ void k_deg(const int* __restrict__ dst, int* __restrict__ deg, int E) {
    int e = blockIdx.x * blockDim.x + threadIdx.x;
    if (e < E) atomicAdd(&deg[dst[e]], 1);
}

// ---- scan (row_ptr over deg+1) ----
__global__ void k_scan1(const int* __restrict__ deg, int* __restrict__ partial,
                        int* __restrict__ bsums, int N) {
    __shared__ int s[256];
    int n = blockIdx.x * 256 + threadIdx.x;
    int v = (n < N) ? (deg[n] + 1) : 0;  // +1 for self-loop
    s[threadIdx.x] = v;
    __syncthreads();
    for (int off = 1; off < 256; off <<= 1) {
        int t = (threadIdx.x >= off) ? s[threadIdx.x - off] : 0;
        __syncthreads();
        s[threadIdx.x] += t;
        __syncthreads();
    }
    if (n < N) partial[n] = s[threadIdx.x];
    if (threadIdx.x == 255) bsums[blockIdx.x] = s[255];
}
__global__ void k_scan2(int* __restrict__ bsums, int nb) {
    __shared__ int s[256];
    int v = (threadIdx.x < nb) ? bsums[threadIdx.x] : 0;
    s[threadIdx.x] = v;
    __syncthreads();
    for (int off = 1; off < 256; off <<= 1) {
        int t = (threadIdx.x >= off) ? s[threadIdx.x - off] : 0;
        __syncthreads();
        s[threadIdx.x] += t;
        __syncthreads();
    }
    bsums[threadIdx.x] = s[threadIdx.x];
}
__global__ void k_scan3(const int* __restrict__ partial, const int* __restrict__ bsums,
                        int* __restrict__ row_ptr, int N) {
    int n = blockIdx.x * 256 + threadIdx.x;
    if (n >= N) return;
    int add = (blockIdx.x > 0) ? bsums[blockIdx.x - 1] : 0;
    row_ptr[n + 1] = partial[n] + add;
    if (n == 0) row_ptr[0] = 0;
}

// ---- CSR fill: eid (slot->edge), src_csr (slot->src node), epos (edge->slot) ----
__global__ void k_csr_fill(const int* __restrict__ ei, int* __restrict__ cursor,
                           int* __restrict__ eid, int* __restrict__ src_csr,
                           int* __restrict__ epos, int E, int Etot) {
    int e = blockIdx.x * blockDim.x + threadIdx.x;
    if (e >= Etot) return;
    int s, d;
    if (e < E) { s = ei[e]; d = ei[E + e]; }
    else { s = e - E; d = e - E; }
    int pos = atomicAdd(&cursor[d], 1);
    eid[pos] = e;
    src_csr[pos] = s;
    epos[e] = pos;
}

// ---- loop_attr by CSR gather: mean of incoming real-edge attrs (wave per node) ----
__global__ void k_loop_gather(const int* __restrict__ row_ptr, const int* __restrict__ eid,
                              const float* __restrict__ ea, float* __restrict__ loop_attr,
                              int N, int E) {
    int w = blockIdx.x * 4 + (threadIdx.x >> 6);
    int lane = threadIdx.x & 63;
    if (w >= N) return;
    int beg = row_ptr[w], end = row_ptr[w + 1];
    float acc = 0.f;
    for (int i = beg; i < end; ++i) {
        int e = eid[i];
        if (e < E) acc += ea[(size_t)e * EDIM + lane];
    }
    float d = fmaxf((float)(end - beg - 1), 1.0f);  // real in-degree, clamped
    loop_attr[(size_t)w * EDIM + lane] = acc / d;
}

// ---- small v precompute: vg[k*12 + l*4 + h] = sum_c We_l[k,h*32+c]*ae_l[h,c] ----
__global__ void k_prep_v(const float* __restrict__ We1, const float* __restrict__ ae1,
                         const float* __restrict__ We2, const float* __restrict__ ae2,
                         const float* __restrict__ We3, const float* __restrict__ ae3,
                         float* __restrict__ vg) {
    int j = threadIdx.x;
    const float* Wes[3] = {We1, We2, We3};
    const float* aes[3] = {ae1, ae2, ae3};
    for (; j < EDIM * 12; j += 256) {
        int k = j / 12, m = j % 12;
        int l = m >> 2, h = m & 3;
        const float* We = Wes[l];
        const float* ae = aes[l];
        float acc = 0.f;
        #pragma unroll
        for (int c = 0; c < 32; ++c) acc += We[k * DM + h * 32 + c] * ae[h * 32 + c];
        vg[j] = acc;
    }
}

// ---- alpha_e for all 3 layers: tall-skinny GEMM, 4 edges/thread, no shuffles ----
__global__ __launch_bounds__(256) void k_alpha_e2(const float* __restrict__ ea,
                                                  const float* __restrict__ loop_attr,
                                                  const float* __restrict__ vg,
                                                  float* __restrict__ alpha_e,
                                                  int E, int Etot) {
    __shared__ float vT[12][64];  // vT[m][k]
    for (int j = threadIdx.x; j < EDIM * 12; j += 256) {
        int k = j & 63, m = j >> 6;
        vT[m][k] = vg[k * 12 + m];
    }
    __syncthreads();
    int base = (blockIdx.x * 256 + threadIdx.x) * 4;
    const float4* rows[4];
    #pragma unroll
    for (int i = 0; i < 4; ++i) {
        int e = base + i;
        if (e < Etot)
            rows[i] = (e < E) ? (const float4*)(ea + (size_t)e * EDIM)
                              : (const float4*)(loop_attr + (size_t)(e - E) * EDIM);
        else
            rows[i] = (const float4*)ea;  // safe dummy, store guarded
    }
    float acc[4][12];
    #pragma unroll
    for (int i = 0; i < 4; ++i)
        #pragma unroll
        for (int m = 0; m < 12; ++m) acc[i][m] = 0.f;
    #pragma unroll 4
    for (int k4 = 0; k4 < 16; ++k4) {
        float4 evv[4];
        #pragma unroll
        for (int i = 0; i < 4; ++i) evv[i] = rows[i][k4];
        #pragma unroll
        for (int m = 0; m < 12; ++m) {
            float4 vv = *(const float4*)&vT[m][k4 * 4];
            #pragma unroll
            for (int i = 0; i < 4; ++i) {
                acc[i][m] += evv[i].x * vv.x + evv[i].y * vv.y +
                             evv[i].z * vv.z + evv[i].w * vv.w;
            }
        }
    }
    #pragma unroll
    for (int i = 0; i < 4; ++i) {
        int e = base + i;
        if (e >= Etot) continue;
        #pragma unroll
        for (int l = 0; l < 3; ++l) {
            float4 o = make_float4(acc[i][l * 4 + 0], acc[i][l * 4 + 1],
                                   acc[i][l * 4 + 2], acc[i][l * 4 + 3]);
            *(float4*)&alpha_e[((size_t)l * Etot + e) * HEADS] = o;
        }
    }
}

// ---- GEMM: out[M,128] = A[M,128] @ W[128,128] (+bias); 4 rows x 4 cols / thread ----
__global__ __launch_bounds__(256) void k_gemm128v2(const float* __restrict__ A,
                                                   const float* __restrict__ W,
                                                   const float* __restrict__ bias,
                                                   float* __restrict__ out, int M) {
    __shared__ float Wl[DM * DM];  // 64 KB
    int tx = threadIdx.x;
    {
        float4* Wl4 = (float4*)Wl;
        const float4* W4 = (const float4*)W;
        for (int i = tx; i < DM * DM / 4; i += 256) Wl4[i] = W4[i];
    }
    __syncthreads();
    int colg = tx & 31;                      // 32 col groups of 4
    int row0 = blockIdx.x * 32 + (tx >> 5) * 4;  // 8 row groups of 4
    const float* aptr[4];
    bool valid[4];
    #pragma unroll
    for (int r = 0; r < 4; ++r) {
        int rr = row0 + r;
        valid[r] = rr < M;
        aptr[r] = A + (size_t)(valid[r] ? rr : (M - 1)) * DM;
    }
    float4 acc[4] = {{0,0,0,0},{0,0,0,0},{0,0,0,0},{0,0,0,0}};
    for (int k4 = 0; k4 < DM / 4; ++k4) {
        float4 a4[4];
        #pragma unroll
        for (int r = 0; r < 4; ++r) a4[r] = *(const float4*)&aptr[r][k4 * 4];
        #pragma unroll
        for (int j = 0; j < 4; ++j) {
            float4 w4 = *(const float4*)&Wl[(k4 * 4 + j) * DM + colg * 4];
            #pragma unroll
            for (int r = 0; r < 4; ++r) {
                float av = ((const float*)&a4[r])[j];
                acc[r].x += av * w4.x;
                acc[r].y += av * w4.y;
                acc[r].z += av * w4.z;
                acc[r].w += av * w4.w;
            }
        }
    }
    float4 bv = {0, 0, 0, 0};
    if (bias) bv = *(const float4*)&bias[colg * 4];
    #pragma unroll
    for (int r = 0; r < 4; ++r) {
        if (!valid[r]) continue;
        float4 o = make_float4(acc[r].x + bv.x, acc[r].y + bv.y,
                               acc[r].z + bv.z, acc[r].w + bv.w);
        *(float4*)&out[(size_t)(row0 + r) * DM + colg * 4] = o;
    }
}

// ---- per-node attention coefficients ----
__global__ void k_attn_coeff(const float* __restrict__ xh, const float* __restrict__ a_s,
                             const float* __restrict__ a_d, float* __restrict__ as_n,
                             float* __restrict__ ad_n, int N) {
    int i = blockIdx.x * blockDim.x + threadIdx.x;
    if (i >= N * HEADS) return;
    int n = i >> 2, h = i & 3;
    const float* v = xh + (size_t)n * DM + h * 32;
    float s1 = 0.f, s2 = 0.f;
    #pragma unroll
    for (int c = 0; c < 32; ++c) {
        float xv = v[c];
        s1 += xv * a_s[h * 32 + c];
        s2 += xv * a_d[h * 32 + c];
    }
    as_n[i] = s1;
    ad_n[i] = s2;
}

// ---- logits + leaky_relu, scattered directly into CSR-slot order ----
__global__ void k_logits(const int* __restrict__ ei, const int* __restrict__ epos,
                         const float* __restrict__ as_n, const float* __restrict__ ad_n,
                         const float* __restrict__ alpha_e_l, float* __restrict__ att_s,
                         int E, int Etot) {
    int e = blockIdx.x * blockDim.x + threadIdx.x;
    if (e >= Etot) return;
    int s, d;
    if (e < E) { s = ei[e]; d = ei[E + e]; }
    else { s = e - E; d = e - E; }
    float4 as4 = *(const float4*)&as_n[s * HEADS];
    float4 ad4 = *(const float4*)&ad_n[d * HEADS];
    float4 al4 = *(const float4*)&alpha_e_l[(size_t)e * HEADS];
    float4 o;
    float l0 = as4.x + ad4.x + al4.x; o.x = (l0 >= 0.f) ? l0 : 0.2f * l0;
    float l1 = as4.y + ad4.y + al4.y; o.y = (l1 >= 0.f) ? l1 : 0.2f * l1;
    float l2 = as4.z + ad4.z + al4.z; o.z = (l2 >= 0.f) ? l2 : 0.2f * l2;
    float l3 = as4.w + ad4.w + al4.w; o.w = (l3 >= 0.f) ? l3 : 0.2f * l3;
    *(float4*)&att_s[(size_t)epos[e] * HEADS] = o;
}

// ---- segment softmax over CSR-slot-ordered att_s (wave per node, sequential) ----
__global__ void k_softmax(const int* __restrict__ row_ptr, float* __restrict__ att_s, int N) {
    int w = blockIdx.x * 4 + (threadIdx.x >> 6);
    int lane = threadIdx.x & 63;
    if (w >= N) return;
    int beg = row_ptr[w], end = row_ptr[w + 1];
    const float4* a4 = (const float4*)att_s;
    float m0 = -INFINITY, m1 = -INFINITY, m2 = -INFINITY, m3 = -INFINITY;
    for (int i = beg + lane; i < end; i += 64) {
        float4 a = a4[i];
        m0 = fmaxf(m0, a.x); m1 = fmaxf(m1, a.y);
        m2 = fmaxf(m2, a.z); m3 = fmaxf(m3, a.w);
    }
    m0 = wred_max(m0); m1 = wred_max(m1); m2 = wred_max(m2); m3 = wred_max(m3);
    float s0 = 0.f, s1 = 0.f, s2 = 0.f, s3 = 0.f;
    for (int i = beg + lane; i < end; i += 64) {
        float4 a = a4[i];
        s0 += __expf(a.x - m0); s1 += __expf(a.y - m1);
        s2 += __expf(a.z - m2); s3 += __expf(a.w - m3);
    }
    s0 = wred_sum(s0); s1 = wred_sum(s1); s2 = wred_sum(s2); s3 = wred_sum(s3);
    float r0 = 1.f / s0, r1 = 1.f / s1, r2 = 1.f / s2, r3 = 1.f / s3;
    for (int i = beg + lane; i < end; i += 64) {
        float4 a = a4[i];
        float4 o = make_float4(__expf(a.x - m0) * r0, __expf(a.y - m1) * r1,
                               __expf(a.z - m2) * r2, __expf(a.w - m3) * r3);
        *(float4*)&att_s[(size_t)i * HEADS] = o;
    }
}

// ---- aggregation + mean + bias + residual + relu (wave per node) ----
__global__ void k_aggregate(const int* __restrict__ row_ptr, const int* __restrict__ src_csr,
                            const float* __restrict__ att_s, const float* __restrict__ xh,
                            const float* __restrict__ hin, const float* __restrict__ bias,
                            float* __restrict__ hout, int N) {
    int w = blockIdx.x * 4 + (threadIdx.x >> 6);
    int lane = threadIdx.x & 63;
    if (w >= N) return;
    int beg = row_ptr[w], end = row_ptr[w + 1];
    int f0 = lane, f1 = lane + 64;
    int h0 = lane >> 5;        // heads 0/1
    int h1 = 2 + (lane >> 5);  // heads 2/3
    float acc0 = 0.f, acc1 = 0.f;
    for (int i = beg; i < end; ++i) {
        int s = src_csr[i];
        float a0 = att_s[(size_t)i * HEADS + h0];
        float a1 = att_s[(size_t)i * HEADS + h1];
        acc0 += a0 * xh[(size_t)s * DM + f0];
        acc1 += a1 * xh[(size_t)s * DM + f1];
    }
    float cnt = (float)(end - beg);
    float o0 = acc0 / cnt + bias[f0] + hin[(size_t)w * DM + f0];
    float o1 = acc1 / cnt + bias[f1] + hin[(size_t)w * DM + f1];
    hout[(size_t)w * DM + f0] = fmaxf(o0, 0.f);
    hout[(size_t)w * DM + f1] = fmaxf(o1, 0.f);
}

extern "C" void kernel_launch(void* const* d_in, const int* in_sizes, int n_in,
                              void* d_out, int out_size, void* d_ws, size_t ws_size,
                              hipStream_t stream) {
    const float* x = (const float*)d_in[0];
    const int* ei = (const int*)d_in[1];
    const float* edge_attr = (const float*)d_in[2];
    const float* lp_W = (const float*)d_in[3];
    const float* lp_b = (const float*)d_in[4];
    int N = in_sizes[0] / DM;
    int E = in_sizes[1] / 2;
    int Etot = E + N;
    float* out = (float*)d_out;

    char* p = (char*)d_ws;
    auto alloc = [&](size_t bytes) {
        char* r = p;
        p += (bytes + 255) & ~(size_t)255;
        return r;
    };
    float* h = (float*)alloc((size_t)N * DM * 4);
    float* xh = (float*)alloc((size_t)N * DM * 4);
    float* loop_attr = (float*)alloc((size_t)N * EDIM * 4);
    float* alpha_e = (float*)alloc((size_t)3 * Etot * HEADS * 4);
    float* att_s = (float*)alloc((size_t)Etot * HEADS * 4);
    float* as_n = (float*)alloc((size_t)N * HEADS * 4);
    float* ad_n = (float*)alloc((size_t)N * HEADS * 4);
    float* vg = (float*)alloc(EDIM * 12 * 4);
    int* deg = (int*)alloc((size_t)N * 4);
    int* row_ptr = (int*)alloc((size_t)(N + 1) * 4);
    int* partial = (int*)alloc((size_t)N * 4);  // reused as cursor after scan
    int* eid = (int*)alloc((size_t)Etot * 4);
    int* src_csr = (int*)alloc((size_t)Etot * 4);
    int* epos = (int*)alloc((size_t)Etot * 4);
    int* bsums = (int*)alloc(256 * 4);
    int* cursor = partial;  // alias: partial consumed by scan3 before csr_fill

    hipMemsetAsync(deg, 0, (size_t)N * 4, stream);

    k_deg<<<(E + 255) / 256, 256, 0, stream>>>(ei + E, deg, E);

    int nb = (N + 255) / 256;
    k_scan1<<<nb, 256, 0, stream>>>(deg, partial, bsums, N);
    k_scan2<<<1, 256, 0, stream>>>(bsums, nb);
    k_scan3<<<nb, 256, 0, stream>>>(partial, bsums, row_ptr, N);
    hipMemcpyAsync(cursor, row_ptr, (size_t)N * 4, hipMemcpyDeviceToDevice, stream);
    k_csr_fill<<<(Etot + 255) / 256, 256, 0, stream>>>(ei, cursor, eid, src_csr, epos, E, Etot);
    k_loop_gather<<<(N + 3) / 4, 256, 0, stream>>>(row_ptr, eid, edge_attr, loop_attr, N, E);

    k_prep_v<<<1, 256, 0, stream>>>((const float*)d_in[8], (const float*)d_in[9],
                                    (const float*)d_in[14], (const float*)d_in[15],
                                    (const float*)d_in[20], (const float*)d_in[21], vg);
    k_alpha_e2<<<(Etot + 1023) / 1024, 256, 0, stream>>>(edge_attr, loop_attr, vg,
                                                         alpha_e, E, Etot);

    k_gemm128v2<<<(N + 31) / 32, 256, 0, stream>>>(x, lp_W, lp_b, h, N);

    for (int l = 0; l < 3; ++l) {
        const float* W = (const float*)d_in[5 + 6 * l];
        const float* a_s = (const float*)d_in[6 + 6 * l];
        const float* a_d = (const float*)d_in[7 + 6 * l];
        const float* b = (const float*)d_in[10 + 6 * l];
        k_gemm128v2<<<(N + 31) / 32, 256, 0, stream>>>(h, W, nullptr, xh, N);
        k_attn_coeff<<<(N * HEADS + 255) / 256, 256, 0, stream>>>(xh, a_s, a_d, as_n, ad_n, N);
        k_logits<<<(Etot + 255) / 256, 256, 0, stream>>>(ei, epos, as_n, ad_n,
                                                         alpha_e + (size_t)l * Etot * HEADS,
                                                         att_s, E, Etot);
        k_softmax<<<(N + 3) / 4, 256, 0, stream>>>(row_ptr, att_s, N);
        float* hout = (l == 2) ? out : h;
        k_aggregate<<<(N + 3) / 4, 256, 0, stream>>>(row_ptr, src_csr, att_s, xh, h, b, hout, N);
    }
}

// Round 9
// 1029.492 us; speedup vs baseline: 2.3774x; 1.2484x over previous
//
#include <hip/hip_runtime.h>
#include <cmath>

#define HEADS 4
#define DM 128
#define EDIM 64
#define CAP 128  // max cached slots per node (Poisson(16) in-degree: P(>120)~0)

__device__ __forceinline__ float wred_max(float v) {
    #pragma unroll
    for (int off = 32; off; off >>= 1) v = fmaxf(v, __shfl_xor(v, off, 64));
    return v;
}
__device__ __forceinline__ float wred_sum(float v) {
    #pragma unroll
    for (int off = 32; off; off >>= 1) v += __shfl_xor(v, off, 64);
    return v;
}

// ---- degree count over dst ----
__global__ void k_deg(const int* __restrict__ dst, int* __restrict__ deg, int E) {
    int e = blockIdx.x * blockDim.x + threadIdx.x;
    if (e < E) atomicAdd(&deg[dst[e]], 1);
}

// ---- scan (row_ptr over deg+1) ----
__global__ void k_scan1(const int* __restrict__ deg, int* __restrict__ partial,
                        int* __restrict__ bsums, int N) {
    __shared__ int s[256];
    int n = blockIdx.x * 256 + threadIdx.x;
    int v = (n < N) ? (deg[n] + 1) : 0;  // +1 for self-loop
    s[threadIdx.x] = v;
    __syncthreads();
    for (int off = 1; off < 256; off <<= 1) {
        int t = (threadIdx.x >= off) ? s[threadIdx.x - off] : 0;
        __syncthreads();
        s[threadIdx.x] += t;
        __syncthreads();
    }
    if (n < N) partial[n] = s[threadIdx.x];
    if (threadIdx.x == 255) bsums[blockIdx.x] = s[255];
}
__global__ void k_scan2(int* __restrict__ bsums, int nb) {
    __shared__ int s[256];
    int v = (threadIdx.x < nb) ? bsums[threadIdx.x] : 0;
    s[threadIdx.x] = v;
    __syncthreads();
    for (int off = 1; off < 256; off <<= 1) {
        int t = (threadIdx.x >= off) ? s[threadIdx.x - off] : 0;
        __syncthreads();
        s[threadIdx.x] += t;
        __syncthreads();
    }
    bsums[threadIdx.x] = s[threadIdx.x];
}
__global__ void k_scan3(const int* __restrict__ partial, const int* __restrict__ bsums,
                        int* __restrict__ row_ptr, int N) {
    int n = blockIdx.x * 256 + threadIdx.x;
    if (n >= N) return;
    int add = (blockIdx.x > 0) ? bsums[blockIdx.x - 1] : 0;
    row_ptr[n + 1] = partial[n] + add;
    if (n == 0) row_ptr[0] = 0;
}

// ---- CSR fill: src_csr (slot->src node), epos (edge->slot) ----
__global__ void k_csr_fill(const int* __restrict__ ei, int* __restrict__ cursor,
                           int* __restrict__ src_csr, int* __restrict__ epos,
                           int E, int Etot) {
    int e = blockIdx.x * blockDim.x + threadIdx.x;
    if (e >= Etot) return;
    int s, d;
    if (e < E) { s = ei[e]; d = ei[E + e]; }
    else { s = e - E; d = e - E; }
    int pos = atomicAdd(&cursor[d], 1);
    src_csr[pos] = s;
    epos[e] = pos;
}

// ---- small v precompute: vg[k*12 + l*4 + h] = sum_c We_l[k,h*32+c]*ae_l[h,c] ----
__global__ void k_prep_v(const float* __restrict__ We1, const float* __restrict__ ae1,
                         const float* __restrict__ We2, const float* __restrict__ ae2,
                         const float* __restrict__ We3, const float* __restrict__ ae3,
                         float* __restrict__ vg) {
    int j = threadIdx.x;
    const float* Wes[3] = {We1, We2, We3};
    const float* aes[3] = {ae1, ae2, ae3};
    for (; j < EDIM * 12; j += 256) {
        int k = j / 12, m = j % 12;
        int l = m >> 2, h = m & 3;
        const float* We = Wes[l];
        const float* ae = aes[l];
        float acc = 0.f;
        #pragma unroll
        for (int c = 0; c < 32; ++c) acc += We[k * DM + h * 32 + c] * ae[h * 32 + c];
        vg[j] = acc;
    }
}

// ---- alpha for REAL edges, all 3 layers; scattered to CSR-slot order ----
// alpha_s layout: 3 arrays of [Etot][4], alpha_s + l*Etot*4
__global__ __launch_bounds__(256) void k_alpha_e3(const float* __restrict__ ea,
                                                  const int* __restrict__ epos,
                                                  const float* __restrict__ vg,
                                                  float* __restrict__ alpha_s,
                                                  int E, int Etot) {
    __shared__ float vT[12][64];  // vT[m][k]
    for (int j = threadIdx.x; j < EDIM * 12; j += 256) {
        int k = j & 63, m = j >> 6;
        vT[m][k] = vg[k * 12 + m];
    }
    __syncthreads();
    int base = (blockIdx.x * 256 + threadIdx.x) * 4;
    if (base >= E) return;
    float acc[4][12];
    #pragma unroll
    for (int i = 0; i < 4; ++i)
        #pragma unroll
        for (int m = 0; m < 12; ++m) acc[i][m] = 0.f;
    #pragma unroll 4
    for (int k4 = 0; k4 < 16; ++k4) {
        float4 evv[4];
        #pragma unroll
        for (int i = 0; i < 4; ++i) {
            int e = base + i;
            evv[i] = (e < E) ? *(const float4*)(ea + (size_t)e * EDIM + k4 * 4)
                             : make_float4(0.f, 0.f, 0.f, 0.f);
        }
        #pragma unroll
        for (int m = 0; m < 12; ++m) {
            float4 vv = *(const float4*)&vT[m][k4 * 4];
            #pragma unroll
            for (int i = 0; i < 4; ++i) {
                acc[i][m] += evv[i].x * vv.x + evv[i].y * vv.y +
                             evv[i].z * vv.z + evv[i].w * vv.w;
            }
        }
    }
    #pragma unroll
    for (int i = 0; i < 4; ++i) {
        int e = base + i;
        if (e >= E) continue;
        int pos = epos[e];
        #pragma unroll
        for (int l = 0; l < 3; ++l) {
            float4 o = make_float4(acc[i][l * 4 + 0], acc[i][l * 4 + 1],
                                   acc[i][l * 4 + 2], acc[i][l * 4 + 3]);
            *(float4*)&alpha_s[((size_t)l * Etot + pos) * HEADS] = o;
        }
    }
}

// ---- self-loop alpha = mean of node's real-edge alphas (thread per node) ----
__global__ void k_self_alpha(const int* __restrict__ row_ptr, const int* __restrict__ epos,
                             float* __restrict__ alpha_s, int N, int E, int Etot) {
    int n = blockIdx.x * 256 + threadIdx.x;
    if (n >= N) return;
    int beg = row_ptr[n], end = row_ptr[n + 1];
    int self = epos[E + n];
    float4 s0 = {0, 0, 0, 0}, s1 = {0, 0, 0, 0}, s2 = {0, 0, 0, 0};
    float* a0 = alpha_s;
    float* a1 = alpha_s + (size_t)Etot * HEADS;
    float* a2 = alpha_s + (size_t)2 * Etot * HEADS;
    for (int i = beg; i < end; ++i) {
        if (i == self) continue;
        float4 v0 = *(const float4*)&a0[(size_t)i * HEADS];
        float4 v1 = *(const float4*)&a1[(size_t)i * HEADS];
        float4 v2 = *(const float4*)&a2[(size_t)i * HEADS];
        s0.x += v0.x; s0.y += v0.y; s0.z += v0.z; s0.w += v0.w;
        s1.x += v1.x; s1.y += v1.y; s1.z += v1.z; s1.w += v1.w;
        s2.x += v2.x; s2.y += v2.y; s2.z += v2.z; s2.w += v2.w;
    }
    float r = 1.f / fmaxf((float)(end - beg - 1), 1.0f);
    *(float4*)&a0[(size_t)self * HEADS] = make_float4(s0.x * r, s0.y * r, s0.z * r, s0.w * r);
    *(float4*)&a1[(size_t)self * HEADS] = make_float4(s1.x * r, s1.y * r, s1.z * r, s1.w * r);
    *(float4*)&a2[(size_t)self * HEADS] = make_float4(s2.x * r, s2.y * r, s2.z * r, s2.w * r);
}

// ---- GEMM: out[M,128] = A[M,128] @ W[128,128] (+bias); 4 rows x 4 cols / thread ----
__global__ __launch_bounds__(256) void k_gemm128v2(const float* __restrict__ A,
                                                   const float* __restrict__ W,
                                                   const float* __restrict__ bias,
                                                   float* __restrict__ out, int M) {
    __shared__ float Wl[DM * DM];  // 64 KB
    int tx = threadIdx.x;
    {
        float4* Wl4 = (float4*)Wl;
        const float4* W4 = (const float4*)W;
        for (int i = tx; i < DM * DM / 4; i += 256) Wl4[i] = W4[i];
    }
    __syncthreads();
    int colg = tx & 31;
    int row0 = blockIdx.x * 32 + (tx >> 5) * 4;
    const float* aptr[4];
    bool valid[4];
    #pragma unroll
    for (int r = 0; r < 4; ++r) {
        int rr = row0 + r;
        valid[r] = rr < M;
        aptr[r] = A + (size_t)(valid[r] ? rr : (M - 1)) * DM;
    }
    float4 acc[4] = {{0,0,0,0},{0,0,0,0},{0,0,0,0},{0,0,0,0}};
    for (int k4 = 0; k4 < DM / 4; ++k4) {
        float4 a4[4];
        #pragma unroll
        for (int r = 0; r < 4; ++r) a4[r] = *(const float4*)&aptr[r][k4 * 4];
        #pragma unroll
        for (int j = 0; j < 4; ++j) {
            float4 w4 = *(const float4*)&Wl[(k4 * 4 + j) * DM + colg * 4];
            #pragma unroll
            for (int r = 0; r < 4; ++r) {
                float av = ((const float*)&a4[r])[j];
                acc[r].x += av * w4.x;
                acc[r].y += av * w4.y;
                acc[r].z += av * w4.z;
                acc[r].w += av * w4.w;
            }
        }
    }
    float4 bv = {0, 0, 0, 0};
    if (bias) bv = *(const float4*)&bias[colg * 4];
    #pragma unroll
    for (int r = 0; r < 4; ++r) {
        if (!valid[r]) continue;
        float4 o = make_float4(acc[r].x + bv.x, acc[r].y + bv.y,
                               acc[r].z + bv.z, acc[r].w + bv.w);
        *(float4*)&out[(size_t)(row0 + r) * DM + colg * 4] = o;
    }
}

// ---- per-node attention coefficients ----
__global__ void k_attn_coeff(const float* __restrict__ xh, const float* __restrict__ a_s,
                             const float* __restrict__ a_d, float* __restrict__ as_n,
                             float* __restrict__ ad_n, int N) {
    int i = blockIdx.x * blockDim.x + threadIdx.x;
    if (i >= N * HEADS) return;
    int n = i >> 2, h = i & 3;
    const float* v = xh + (size_t)n * DM + h * 32;
    float s1 = 0.f, s2 = 0.f;
    #pragma unroll
    for (int c = 0; c < 32; ++c) {
        float xv = v[c];
        s1 += xv * a_s[h * 32 + c];
        s2 += xv * a_d[h * 32 + c];
    }
    as_n[i] = s1;
    ad_n[i] = s2;
}

// ---- fused logits + leaky + segment-softmax + mean-aggregate + bias+res+relu ----
// wave per node; logits cached in LDS (recompute fallback for cnt > CAP)
__global__ __launch_bounds__(256) void k_attn_fused(
        const int* __restrict__ row_ptr, const int* __restrict__ src_csr,
        const float* __restrict__ alpha_l, const float* __restrict__ as_n,
        const float* __restrict__ ad_n, const float* __restrict__ xh,
        const float* __restrict__ hin, const float* __restrict__ bias,
        float* __restrict__ hout, int N) {
    __shared__ float sm[4][CAP][HEADS];
    int wv = threadIdx.x >> 6;
    int lane = threadIdx.x & 63;
    int w = blockIdx.x * 4 + wv;
    if (w >= N) return;
    int beg = row_ptr[w], end = row_ptr[w + 1];
    int cnt = end - beg;
    float4 ad4 = *(const float4*)&ad_n[w * HEADS];
    float m0 = -INFINITY, m1 = -INFINITY, m2 = -INFINITY, m3 = -INFINITY;
    float s0 = 0.f, s1 = 0.f, s2 = 0.f, s3 = 0.f;
    if (cnt <= CAP) {
        for (int i = beg + lane; i < end; i += 64) {
            int s = src_csr[i];
            float4 as4 = *(const float4*)&as_n[s * HEADS];
            float4 al4 = *(const float4*)&alpha_l[(size_t)i * HEADS];
            float l0 = as4.x + ad4.x + al4.x; l0 = (l0 >= 0.f) ? l0 : 0.2f * l0;
            float l1 = as4.y + ad4.y + al4.y; l1 = (l1 >= 0.f) ? l1 : 0.2f * l1;
            float l2 = as4.z + ad4.z + al4.z; l2 = (l2 >= 0.f) ? l2 : 0.2f * l2;
            float l3 = as4.w + ad4.w + al4.w; l3 = (l3 >= 0.f) ? l3 : 0.2f * l3;
            *(float4*)&sm[wv][i - beg][0] = make_float4(l0, l1, l2, l3);
            m0 = fmaxf(m0, l0); m1 = fmaxf(m1, l1);
            m2 = fmaxf(m2, l2); m3 = fmaxf(m3, l3);
        }
        m0 = wred_max(m0); m1 = wred_max(m1); m2 = wred_max(m2); m3 = wred_max(m3);
        for (int i = beg + lane; i < end; i += 64) {
            float4 l4 = *(const float4*)&sm[wv][i - beg][0];
            float e0 = __expf(l4.x - m0), e1 = __expf(l4.y - m1);
            float e2 = __expf(l4.z - m2), e3 = __expf(l4.w - m3);
            *(float4*)&sm[wv][i - beg][0] = make_float4(e0, e1, e2, e3);
            s0 += e0; s1 += e1; s2 += e2; s3 += e3;
        }
        s0 = wred_sum(s0); s1 = wred_sum(s1); s2 = wred_sum(s2); s3 = wred_sum(s3);
        int h0 = lane >> 5;  // heads 0/1 for f0
        float rA = (h0 ? 1.f / s1 : 1.f / s0);
        float rB = (h0 ? 1.f / s3 : 1.f / s2);
        int f0 = lane, f1 = lane + 64;
        float acc0 = 0.f, acc1 = 0.f;
        int j = 0;
        for (; j + 1 < cnt; j += 2) {
            int sA = src_csr[beg + j];
            int sB = src_csr[beg + j + 1];
            float aA0 = sm[wv][j][h0], aA1 = sm[wv][j][2 + h0];
            float aB0 = sm[wv][j + 1][h0], aB1 = sm[wv][j + 1][2 + h0];
            float xA0 = xh[(size_t)sA * DM + f0], xA1 = xh[(size_t)sA * DM + f1];
            float xB0 = xh[(size_t)sB * DM + f0], xB1 = xh[(size_t)sB * DM + f1];
            acc0 += aA0 * xA0 + aB0 * xB0;
            acc1 += aA1 * xA1 + aB1 * xB1;
        }
        if (j < cnt) {
            int sA = src_csr[beg + j];
            acc0 += sm[wv][j][h0] * xh[(size_t)sA * DM + f0];
            acc1 += sm[wv][j][2 + h0] * xh[(size_t)sA * DM + f1];
        }
        float rc = 1.f / (float)cnt;
        float o0 = acc0 * rA * rc + bias[f0] + hin[(size_t)w * DM + f0];
        float o1 = acc1 * rB * rc + bias[f1] + hin[(size_t)w * DM + f1];
        hout[(size_t)w * DM + f0] = fmaxf(o0, 0.f);
        hout[(size_t)w * DM + f1] = fmaxf(o1, 0.f);
    } else {
        // cold path: recompute logits each pass
        for (int i = beg + lane; i < end; i += 64) {
            int s = src_csr[i];
            float4 as4 = *(const float4*)&as_n[s * HEADS];
            float4 al4 = *(const float4*)&alpha_l[(size_t)i * HEADS];
            float l0 = as4.x + ad4.x + al4.x; l0 = (l0 >= 0.f) ? l0 : 0.2f * l0;
            float l1 = as4.y + ad4.y + al4.y; l1 = (l1 >= 0.f) ? l1 : 0.2f * l1;
            float l2 = as4.z + ad4.z + al4.z; l2 = (l2 >= 0.f) ? l2 : 0.2f * l2;
            float l3 = as4.w + ad4.w + al4.w; l3 = (l3 >= 0.f) ? l3 : 0.2f * l3;
            m0 = fmaxf(m0, l0); m1 = fmaxf(m1, l1);
            m2 = fmaxf(m2, l2); m3 = fmaxf(m3, l3);
        }
        m0 = wred_max(m0); m1 = wred_max(m1); m2 = wred_max(m2); m3 = wred_max(m3);
        for (int i = beg + lane; i < end; i += 64) {
            int s = src_csr[i];
            float4 as4 = *(const float4*)&as_n[s * HEADS];
            float4 al4 = *(const float4*)&alpha_l[(size_t)i * HEADS];
            float l0 = as4.x + ad4.x + al4.x; l0 = (l0 >= 0.f) ? l0 : 0.2f * l0;
            float l1 = as4.y + ad4.y + al4.y; l1 = (l1 >= 0.f) ? l1 : 0.2f * l1;
            float l2 = as4.z + ad4.z + al4.z; l2 = (l2 >= 0.f) ? l2 : 0.2f * l2;
            float l3 = as4.w + ad4.w + al4.w; l3 = (l3 >= 0.f) ? l3 : 0.2f * l3;
            s0 += __expf(l0 - m0); s1 += __expf(l1 - m1);
            s2 += __expf(l2 - m2); s3 += __expf(l3 - m3);
        }
        s0 = wred_sum(s0); s1 = wred_sum(s1); s2 = wred_sum(s2); s3 = wred_sum(s3);
        int h0 = lane >> 5;
        float rA = (h0 ? 1.f / s1 : 1.f / s0);
        float rB = (h0 ? 1.f / s3 : 1.f / s2);
        float mA = (h0 ? m1 : m0), mB = (h0 ? m3 : m2);
        int f0 = lane, f1 = lane + 64;
        float acc0 = 0.f, acc1 = 0.f;
        for (int j = 0; j < cnt; ++j) {
            int i = beg + j;
            int s = src_csr[i];
            float asA = as_n[s * HEADS + h0], asB = as_n[s * HEADS + 2 + h0];
            float adA = (h0 ? ad4.y : ad4.x), adB = (h0 ? ad4.w : ad4.z);
            float alA = alpha_l[(size_t)i * HEADS + h0];
            float alB = alpha_l[(size_t)i * HEADS + 2 + h0];
            float lA = asA + adA + alA; lA = (lA >= 0.f) ? lA : 0.2f * lA;
            float lB = asB + adB + alB; lB = (lB >= 0.f) ? lB : 0.2f * lB;
            acc0 += __expf(lA - mA) * xh[(size_t)s * DM + f0];
            acc1 += __expf(lB - mB) * xh[(size_t)s * DM + f1];
        }
        float rc = 1.f / (float)cnt;
        float o0 = acc0 * rA * rc + bias[f0] + hin[(size_t)w * DM + f0];
        float o1 = acc1 * rB * rc + bias[f1] + hin[(size_t)w * DM + f1];
        hout[(size_t)w * DM + f0] = fmaxf(o0, 0.f);
        hout[(size_t)w * DM + f1] = fmaxf(o1, 0.f);
    }
}

extern "C" void kernel_launch(void* const* d_in, const int* in_sizes, int n_in,
                              void* d_out, int out_size, void* d_ws, size_t ws_size,
                              hipStream_t stream) {
    const float* x = (const float*)d_in[0];
    const int* ei = (const int*)d_in[1];
    const float* edge_attr = (const float*)d_in[2];
    const float* lp_W = (const float*)d_in[3];
    const float* lp_b = (const float*)d_in[4];
    int N = in_sizes[0] / DM;
    int E = in_sizes[1] / 2;
    int Etot = E + N;
    float* out = (float*)d_out;

    char* p = (char*)d_ws;
    auto alloc = [&](size_t bytes) {
        char* r = p;
        p += (bytes + 255) & ~(size_t)255;
        return r;
    };
    float* h = (float*)alloc((size_t)N * DM * 4);
    float* xh = (float*)alloc((size_t)N * DM * 4);
    float* alpha_s = (float*)alloc((size_t)3 * Etot * HEADS * 4);
    float* as_n = (float*)alloc((size_t)N * HEADS * 4);
    float* ad_n = (float*)alloc((size_t)N * HEADS * 4);
    float* vg = (float*)alloc(EDIM * 12 * 4);
    int* deg = (int*)alloc((size_t)N * 4);
    int* row_ptr = (int*)alloc((size_t)(N + 1) * 4);
    int* partial = (int*)alloc((size_t)N * 4);  // reused as cursor after scan
    int* src_csr = (int*)alloc((size_t)Etot * 4);
    int* epos = (int*)alloc((size_t)Etot * 4);
    int* bsums = (int*)alloc(256 * 4);
    int* cursor = partial;  // alias: partial consumed by scan3 before csr_fill

    hipMemsetAsync(deg, 0, (size_t)N * 4, stream);

    k_deg<<<(E + 255) / 256, 256, 0, stream>>>(ei + E, deg, E);

    int nb = (N + 255) / 256;
    k_scan1<<<nb, 256, 0, stream>>>(deg, partial, bsums, N);
    k_scan2<<<1, 256, 0, stream>>>(bsums, nb);
    k_scan3<<<nb, 256, 0, stream>>>(partial, bsums, row_ptr, N);
    hipMemcpyAsync(cursor, row_ptr, (size_t)N * 4, hipMemcpyDeviceToDevice, stream);
    k_csr_fill<<<(Etot + 255) / 256, 256, 0, stream>>>(ei, cursor, src_csr, epos, E, Etot);

    k_prep_v<<<1, 256, 0, stream>>>((const float*)d_in[8], (const float*)d_in[9],
                                    (const float*)d_in[14], (const float*)d_in[15],
                                    (const float*)d_in[20], (const float*)d_in[21], vg);
    k_alpha_e3<<<(E + 1023) / 1024, 256, 0, stream>>>(edge_attr, epos, vg, alpha_s, E, Etot);
    k_self_alpha<<<(N + 255) / 256, 256, 0, stream>>>(row_ptr, epos, alpha_s, N, E, Etot);

    k_gemm128v2<<<(N + 31) / 32, 256, 0, stream>>>(x, lp_W, lp_b, h, N);

    for (int l = 0; l < 3; ++l) {
        const float* W = (const float*)d_in[5 + 6 * l];
        const float* a_s = (const float*)d_in[6 + 6 * l];
        const float* a_d = (const float*)d_in[7 + 6 * l];
        const float* b = (const float*)d_in[10 + 6 * l];
        k_gemm128v2<<<(N + 31) / 32, 256, 0, stream>>>(h, W, nullptr, xh, N);
        k_attn_coeff<<<(N * HEADS + 255) / 256, 256, 0, stream>>>(xh, a_s, a_d, as_n, ad_n, N);
        float* hout = (l == 2) ? out : h;
        k_attn_fused<<<(N + 3) / 4, 256, 0, stream>>>(row_ptr, src_csr,
                                                      alpha_s + (size_t)l * Etot * HEADS,
                                                      as_n, ad_n, xh, h, b, hout, N);
    }
}